// Round 3
// baseline (130.147 us; speedup 1.0000x reference)
//
#include <hip/hip_runtime.h>
#include <math.h>

#define NQ   10
#define NLAY 4
#define BATCH 4096
#define HID  32
#define NM   20   // 2*NQ

typedef float f2 __attribute__((ext_vector_type(2)));

// ---------------------------------------------------------------------------
// Compile-time tracking of the CNOT ring as a GF(2) linear map.
// col[l][k] = pair-xor mask between storage indices for layer-l gate on wire k
// row[l][k] = parity mask giving logical bit x_k from storage index
// ---------------------------------------------------------------------------
struct Tables {
    unsigned col[NLAY + 1][NQ];
    unsigned row[NLAY + 1][NQ];
};

constexpr Tables make_tables() {
    Tables t{};
    unsigned col[NQ] = {}, row[NQ] = {};
    for (int k = 0; k < NQ; ++k) { col[k] = 1u << (NQ - 1 - k); row[k] = 1u << (NQ - 1 - k); }
    for (int l = 0; l <= NLAY; ++l) {
        for (int k = 0; k < NQ; ++k) { t.col[l][k] = col[k]; t.row[l][k] = row[k]; }
        for (int k = 0; k < NQ; ++k) {            // ring: CNOT(k, (k+1)%NQ)
            int c = k, tg = (k + 1) % NQ;
            col[c] ^= col[tg];
            row[tg] ^= row[c];
        }
    }
    return t;
}

static constexpr Tables TB = make_tables();

__device__ __forceinline__ f2 mk2(float a, float b) { f2 r; r[0] = a; r[1] = b; return r; }
__device__ __forceinline__ f2 ffma(f2 a, f2 b, f2 c) { return __builtin_elementwise_fma(a, b, c); }
__device__ __forceinline__ f2 swap2(f2 a) { return mk2(a[1], a[0]); }

// lane-xor shuffle of an f2 (two b32 shuffles) + optional slot swap
__device__ __forceinline__ f2 sh2(f2 a, int vl, int vs) {
    float lo = a[0], hi = a[1];
    if (vl) { lo = __shfl_xor(lo, vl); hi = __shfl_xor(hi, vl); }
    return vs ? mk2(hi, lo) : mk2(lo, hi);
}

// st' = oc*st + pc*pv  (complex, packed over 2 amplitudes; planar re/im)
__device__ __forceinline__ f2 apply_re(f2 ox, f2 oy, f2 px, f2 py,
                                       f2 ar, f2 ai, f2 br, f2 bi) {
    return ffma(ox, ar, ffma(-oy, ai, ffma(px, br, (-py) * bi)));
}
__device__ __forceinline__ f2 apply_im(f2 ox, f2 oy, f2 px, f2 py,
                                       f2 ar, f2 ai, f2 br, f2 bi) {
    return ffma(ox, ai, ffma(oy, ar, ffma(px, bi, py * br)));
}

// One block = one batch element = 2 waves (128 threads).
// Storage index s (10 bits) = (sUp<<3) | (r<<1) | slot, sUp = tid (bit6 = wave).
__global__ __launch_bounds__(128, 8) void qrh_kernel(
    const float* __restrict__ theta, const float* __restrict__ rotw,
    const float* __restrict__ escale, const float* __restrict__ ebias,
    const float* __restrict__ W1, const float* __restrict__ b1,
    const float* __restrict__ W2, const float* __restrict__ b2,
    float* __restrict__ out)
{
    __shared__ float4 gmat[NLAY * NQ][2];   // [gate][U00,U01 | U11,U10]
    __shared__ f2 xbuf[2][4][128];          // cross-wave exchange: [re/im][reg][sUp]
    __shared__ float fbuf[NM];

    const int tid  = threadIdx.x;
    const int lane = tid & 63;
    const int wv9  = tid >> 6;     // wave within element (storage bit 9)
    const int sUp  = tid;          // storage bits 9..3
    const int b    = blockIdx.x;

    // ---- per-gate 2x2 unitary, lane-parallel (threads 0..39) ----
    if (tid < NLAY * NQ) {
        const int g = tid, l = g / NQ, k = g % NQ;
        const float th = theta[b * NQ + k];
        const int e2 = (l * NQ + k) * 2;
        const float t0 = escale[e2 + 0] * th + ebias[e2 + 0];
        const float t1 = escale[e2 + 1] * th + ebias[e2 + 1];
        float sn0, c0, sn1, c1;
        __sincosf(0.5f * t0, &sn0, &c0);
        __sincosf(0.5f * t1, &sn1, &c1);
        // U_enc = RX(t1) RZ(t0)
        const f2 E00 = mk2( c1 * c0,  -c1 * sn0);
        const f2 E01 = mk2( sn1 * sn0, -sn1 * c0);
        const f2 E10 = mk2(-sn1 * sn0, -sn1 * c0);
        const f2 E11 = mk2( c1 * c0,   c1 * sn0);
        const int r3 = (l * NQ + k) * 3;
        const float w0 = rotw[r3 + 0], w1 = rotw[r3 + 1], w2 = rotw[r3 + 2];
        float cw, sw, ca0, sa0, ca1, sa1;
        __sincosf(0.5f * w1, &sw, &cw);
        __sincosf(0.5f * (w0 + w2), &sa0, &ca0);
        __sincosf(0.5f * (w0 - w2), &sa1, &ca1);
        // U_rot = RZ(w2) RY(w1) RZ(w0)
        const f2 R00 = mk2( cw * ca0, -cw * sa0);
        const f2 R01 = mk2(-sw * ca1, -sw * sa1);
        const f2 R10 = mk2( sw * ca1, -sw * sa1);
        const f2 R11 = mk2( cw * ca0,  cw * sa0);
        auto cm = [](f2 a, f2 bb) { return mk2(a[0]*bb[0] - a[1]*bb[1], a[0]*bb[1] + a[1]*bb[0]); };
        const f2 U00 = cm(R00, E00) + cm(R01, E10);
        const f2 U01 = cm(R00, E01) + cm(R01, E11);
        const f2 U10 = cm(R10, E00) + cm(R11, E10);
        const f2 U11 = cm(R10, E01) + cm(R11, E11);
        gmat[g][0] = make_float4(U00[0], U00[1], U01[0], U01[1]);
        gmat[g][1] = make_float4(U11[0], U11[1], U10[0], U10[1]);
    }
    __syncthreads();

    // ---- state: 8 amps/lane, planar re/im packed 2-per-f2 ----
    f2 sre[4], sim[4];
    #pragma unroll
    for (int r = 0; r < 4; ++r) { sre[r] = mk2(0.03125f, 0.03125f); sim[r] = mk2(0.f, 0.f); }

    #pragma unroll
    for (int l = 0; l < NLAY; ++l) {
        #pragma unroll
        for (int k = 0; k < NQ; ++k) {
            const unsigned v = TB.col[l][k];   // compile-time
            const unsigned m = TB.row[l][k];   // compile-time
            const int vw = (int)(v >> 9) & 1;
            const int dUp = (int)(v >> 3) & 127;
            const int vlane = dUp & 63;
            const int vj = (int)(v & 7u), vr = vj >> 1, vs = vj & 1;
            const unsigned mUp = m >> 3;
            const int mj = (int)(m & 7u), mjr = mj >> 1, mjs = mj & 1;
            const int gi = l * NQ + k;

            const int laneP = mUp ? (__popc((unsigned)sUp & mUp) & 1) : 0;
            const float4 A  = gmat[gi][laneP];
            const float4 Bq = gmat[gi][laneP ^ 1];
            f2 oc[2] = { mk2(A.x, A.y), mk2(Bq.x, Bq.y) };
            f2 pc[2] = { mk2(A.z, A.w), mk2(Bq.z, Bq.w) };
            // packed coefficient variants; variant p used by regs with parity(r&mjr)==p
            f2 ocx[2], ocy[2], pcx[2], pcy[2];
            #pragma unroll
            for (int p_ = 0; p_ < 2; ++p_) {
                const int c0 = p_, c1 = p_ ^ mjs;
                ocx[p_] = mk2(oc[c0][0], oc[c1][0]);
                ocy[p_] = mk2(oc[c0][1], oc[c1][1]);
                pcx[p_] = mk2(pc[c0][0], pc[c1][0]);
                pcy[p_] = mk2(pc[c0][1], pc[c1][1]);
            }

            f2 pre[4], pim[4];
            if (vw) {
                // cross-wave exchange through LDS
                #pragma unroll
                for (int r = 0; r < 4; ++r) { xbuf[0][r][sUp] = sre[r]; xbuf[1][r][sUp] = sim[r]; }
                __syncthreads();
                const int pUp = sUp ^ dUp;
                #pragma unroll
                for (int r = 0; r < 4; ++r) {
                    const f2 qre = xbuf[0][r ^ vr][pUp];
                    const f2 qim = xbuf[1][r ^ vr][pUp];
                    pre[r] = vs ? swap2(qre) : qre;
                    pim[r] = vs ? swap2(qim) : qim;
                }
                __syncthreads();   // WAR: protect xbuf before next exchange
            } else if (vlane) {
                #pragma unroll
                for (int r = 0; r < 4; ++r) {
                    pre[r] = sh2(sre[r ^ vr], vlane, vs);
                    pim[r] = sh2(sim[r ^ vr], vlane, vs);
                }
            } else {
                #pragma unroll
                for (int r = 0; r < 4; ++r) {
                    pre[r] = vs ? swap2(sre[r ^ vr]) : sre[r ^ vr];
                    pim[r] = vs ? swap2(sim[r ^ vr]) : sim[r ^ vr];
                }
            }

            #pragma unroll
            for (int r = 0; r < 4; ++r) {
                const int p_ = __builtin_popcount((unsigned)(r & mjr)) & 1;
                const f2 nre = apply_re(ocx[p_], ocy[p_], pcx[p_], pcy[p_],
                                        sre[r], sim[r], pre[r], pim[r]);
                const f2 nim = apply_im(ocx[p_], ocy[p_], pcx[p_], pcy[p_],
                                        sre[r], sim[r], pre[r], pim[r]);
                sre[r] = nre; sim[r] = nim;
            }
        }
    }

    // ---- measurement: probs then 3-bit FWHT over register index ----
    float w[8];
    #pragma unroll
    for (int r = 0; r < 4; ++r) {
        const f2 p2 = ffma(sre[r], sre[r], sim[r] * sim[r]);
        w[2 * r] = p2[0]; w[2 * r + 1] = p2[1];
    }
    #pragma unroll
    for (int bit = 1; bit < 8; bit <<= 1) {
        #pragma unroll
        for (int j = 0; j < 8; ++j) {
            if (!(j & bit)) {
                const float a = w[j], c = w[j | bit];
                w[j] = a + c; w[j | bit] = a - c;
            }
        }
    }
    // w[t] = sum_j (-1)^{popc(j&t)} p[j]

    float feats[NM];
    #pragma unroll
    for (int f = 0; f < NM; ++f) {
        const unsigned M = (f < NQ) ? TB.row[NLAY][f]
                                    : (TB.row[NLAY][f - NQ] ^ TB.row[NLAY][(f - NQ + 1) % NQ]);
        const unsigned MUp = M >> 3;
        const int Mj = (int)(M & 7u);
        const float s = w[Mj];
        const int lsgn = __popc((unsigned)sUp & MUp) & 1;
        feats[f] = lsgn ? -s : s;
    }
    #pragma unroll
    for (int sh = 1; sh < 64; sh <<= 1) {
        #pragma unroll
        for (int f = 0; f < NM; ++f) feats[f] += __shfl_xor(feats[f], sh);
    }

    // ---- cross-wave reduction + MLP head on wave 0 ----
    if (wv9 == 1 && lane == 0) {
        #pragma unroll
        for (int f = 0; f < NM; ++f) fbuf[f] = feats[f];
    }
    __syncthreads();
    if (wv9 == 0) {
        #pragma unroll
        for (int f = 0; f < NM; ++f) feats[f] += fbuf[f];
        float part = 0.f;
        if (lane < HID) {
            float acc = b1[lane];
            #pragma unroll
            for (int mm = 0; mm < NM; ++mm) acc = fmaf(feats[mm], W1[lane * NM + mm], acc);
            const float sg = 1.f / (1.f + __expf(-acc));
            part = acc * sg * W2[lane];
        }
        #pragma unroll
        for (int sh = 32; sh >= 1; sh >>= 1) part += __shfl_xor(part, sh);
        if (lane == 0) out[b] = part + b2[0];
    }
}

extern "C" void kernel_launch(void* const* d_in, const int* in_sizes, int n_in,
                              void* d_out, int out_size, void* d_ws, size_t ws_size,
                              hipStream_t stream) {
    (void)in_sizes; (void)n_in; (void)out_size; (void)d_ws; (void)ws_size;
    const float* theta = (const float*)d_in[0];
    const float* rotw  = (const float*)d_in[1];
    const float* esc   = (const float*)d_in[2];
    const float* ebi   = (const float*)d_in[3];
    const float* W1    = (const float*)d_in[4];
    const float* b1    = (const float*)d_in[5];
    const float* W2    = (const float*)d_in[6];
    const float* b2    = (const float*)d_in[7];
    float* out = (float*)d_out;

    qrh_kernel<<<BATCH, 128, 0, stream>>>(theta, rotw, esc, ebi, W1, b1, W2, b2, out);
}

// Round 4
// 99.507 us; speedup vs baseline: 1.3079x; 1.3079x over previous
//
#include <hip/hip_runtime.h>
#include <math.h>

#define NQ   10
#define NLAY 4
#define BATCH 4096
#define HID  32
#define NM   20   // 2*NQ

typedef float f2 __attribute__((ext_vector_type(2)));

// ---------------------------------------------------------------------------
// Compile-time tracking of the CNOT ring as a GF(2) linear map.
// col[l][k] = pair-xor mask between storage indices for layer-l gate on wire k
// row[l][k] = parity mask giving logical bit x_k from storage index
// ---------------------------------------------------------------------------
struct Tables {
    unsigned col[NLAY + 1][NQ];
    unsigned row[NLAY + 1][NQ];
};

constexpr Tables make_tables() {
    Tables t{};
    unsigned col[NQ] = {}, row[NQ] = {};
    for (int k = 0; k < NQ; ++k) { col[k] = 1u << (NQ - 1 - k); row[k] = 1u << (NQ - 1 - k); }
    for (int l = 0; l <= NLAY; ++l) {
        for (int k = 0; k < NQ; ++k) { t.col[l][k] = col[k]; t.row[l][k] = row[k]; }
        for (int k = 0; k < NQ; ++k) {            // ring: CNOT(k, (k+1)%NQ)
            int c = k, tg = (k + 1) % NQ;
            col[c] ^= col[tg];
            row[tg] ^= row[c];
        }
    }
    return t;
}

static constexpr Tables TB = make_tables();

__device__ __forceinline__ f2 mk2(float a, float b) { f2 r; r[0] = a; r[1] = b; return r; }
__device__ __forceinline__ f2 ffma(f2 a, f2 b, f2 c) { return __builtin_elementwise_fma(a, b, c); }

// ---- DPP-based lane-xor (VALU pipe; avoids ds_swizzle) --------------------
template<int CTRL>
__device__ __forceinline__ float dppf(float x) {
    return __int_as_float(__builtin_amdgcn_update_dpp(
        0, __float_as_int(x), CTRL, 0xF, 0xF, true));
}

// lane-xor by compile-time MASK; DPP where expressible, ds_swizzle otherwise
template<unsigned MASK>
__device__ __forceinline__ float xlane(float x) {
    if constexpr (MASK == 0u)       return x;
    else if constexpr (MASK == 1u)  return dppf<0xB1>(x);   // quad_perm [1,0,3,2]
    else if constexpr (MASK == 2u)  return dppf<0x4E>(x);   // quad_perm [2,3,0,1]
    else if constexpr (MASK == 3u)  return dppf<0x1B>(x);   // quad_perm [3,2,1,0]
    else if constexpr (MASK == 7u)  return dppf<0x141>(x);  // row_half_mirror
    else if constexpr (MASK == 8u)  return dppf<0x128>(x);  // row_ror:8
    else if constexpr (MASK == 10u) return dppf<0x128>(dppf<0x4E>(x));
    else if constexpr (MASK == 15u) return dppf<0x140>(x);  // row_mirror
    else return __shfl_xor(x, (int)MASK);
}

// st' = oc*st + pc*pv  (complex, packed over 2 amplitudes; planar re/im)
__device__ __forceinline__ f2 apply_re(f2 ox, f2 oy, f2 px, f2 py,
                                       f2 ar, f2 ai, f2 br, f2 bi) {
    return ffma(ox, ar, ffma(-oy, ai, ffma(px, br, (-py) * bi)));
}
__device__ __forceinline__ f2 apply_im(f2 ox, f2 oy, f2 px, f2 py,
                                       f2 ar, f2 ai, f2 br, f2 bi) {
    return ffma(ox, ai, ffma(oy, ar, ffma(px, bi, py * br)));
}

// ---- one single-qubit gate, fully compile-time specialized ----------------
template<int L, int K>
__device__ __forceinline__ void apply_gate(f2 (&sre)[8], f2 (&sim)[8],
                                           const float4 (*gm)[2], const int lane) {
    constexpr unsigned v  = TB.col[L][K];
    constexpr unsigned m  = TB.row[L][K];
    constexpr unsigned vl = v >> 4;
    constexpr int vj = (int)(v & 15u), vr = vj >> 1, vs = vj & 1;
    constexpr unsigned ml = m >> 4;
    constexpr int mj = (int)(m & 15u), mjr = mj >> 1, mjs = mj & 1;
    constexpr int gi = L * NQ + K;

    int laneP = 0;
    if constexpr (ml != 0) laneP = __popc((unsigned)lane & ml) & 1;
    const float4 A = gm[gi][laneP];
    f2 occ[2], pcc[2];
    occ[0] = mk2(A.x, A.y); pcc[0] = mk2(A.z, A.w);
    if constexpr (mj != 0) {
        const float4 Bq = gm[gi][laneP ^ 1];
        occ[1] = mk2(Bq.x, Bq.y); pcc[1] = mk2(Bq.z, Bq.w);
    } else { occ[1] = occ[0]; pcc[1] = pcc[0]; }

    // packed coefficient variants; variant p used by regs with parity(r&mjr)==p
    f2 ocx[2], ocy[2], pcx[2], pcy[2];
    #pragma unroll
    for (int p_ = 0; p_ < 2; ++p_) {
        const f2 a_ = occ[p_], b_ = occ[p_ ^ mjs];
        const f2 c_ = pcc[p_], d_ = pcc[p_ ^ mjs];
        ocx[p_] = mk2(a_[0], b_[0]); ocy[p_] = mk2(a_[1], b_[1]);
        pcx[p_] = mk2(c_[0], d_[0]); pcy[p_] = mk2(c_[1], d_[1]);
    }

    f2 pre[8], pim[8];
    #pragma unroll
    for (int r = 0; r < 8; ++r) {
        const f2 qre = sre[r ^ vr], qim = sim[r ^ vr];
        const float re0 = vs ? qre[1] : qre[0];
        const float re1 = vs ? qre[0] : qre[1];
        const float im0 = vs ? qim[1] : qim[0];
        const float im1 = vs ? qim[0] : qim[1];
        pre[r] = mk2(xlane<vl>(re0), xlane<vl>(re1));
        pim[r] = mk2(xlane<vl>(im0), xlane<vl>(im1));
    }
    #pragma unroll
    for (int r = 0; r < 8; ++r) {
        const int p_ = __builtin_popcount((unsigned)(r & mjr)) & 1;  // constexpr-folds
        const f2 nre = apply_re(ocx[p_], ocy[p_], pcx[p_], pcy[p_],
                                sre[r], sim[r], pre[r], pim[r]);
        const f2 nim = apply_im(ocx[p_], ocy[p_], pcx[p_], pcy[p_],
                                sre[r], sim[r], pre[r], pim[r]);
        sre[r] = nre; sim[r] = nim;
    }
}

template<unsigned SH>
__device__ __forceinline__ void red_stage(float (&f)[NM]) {
    #pragma unroll
    for (int i = 0; i < NM; ++i) f[i] += xlane<SH>(f[i]);
}

__global__ __launch_bounds__(256, 4) void qrh_kernel(
    const float* __restrict__ theta, const float* __restrict__ rotw,
    const float* __restrict__ escale, const float* __restrict__ ebias,
    const float* __restrict__ W1, const float* __restrict__ b1,
    const float* __restrict__ W2, const float* __restrict__ b2,
    float* __restrict__ out)
{
    // per gate: group0 = [U00.re,U00.im,U01.re,U01.im], group1 = [U11.re,U11.im,U10.re,U10.im]
    __shared__ float4 gmat[4][NLAY * NQ][2];

    const int tid  = threadIdx.x;
    const int lane = tid & 63;
    const int wv   = tid >> 6;
    const int b    = blockIdx.x * 4 + wv;

    // ---- per-gate 2x2 unitary, lane-parallel (lanes 0..39) ----
    if (lane < NLAY * NQ) {
        const int g = lane, l = g / NQ, k = g % NQ;
        const float th = theta[b * NQ + k];
        const int e2 = (l * NQ + k) * 2;
        const float t0 = escale[e2 + 0] * th + ebias[e2 + 0];
        const float t1 = escale[e2 + 1] * th + ebias[e2 + 1];
        float sn0, c0, sn1, c1;
        __sincosf(0.5f * t0, &sn0, &c0);
        __sincosf(0.5f * t1, &sn1, &c1);
        // U_enc = RX(t1) RZ(t0)
        const f2 E00 = mk2( c1 * c0,  -c1 * sn0);
        const f2 E01 = mk2( sn1 * sn0, -sn1 * c0);
        const f2 E10 = mk2(-sn1 * sn0, -sn1 * c0);
        const f2 E11 = mk2( c1 * c0,   c1 * sn0);
        const int r3 = (l * NQ + k) * 3;
        const float w0 = rotw[r3 + 0], w1 = rotw[r3 + 1], w2 = rotw[r3 + 2];
        float cw, sw, ca0, sa0, ca1, sa1;
        __sincosf(0.5f * w1, &sw, &cw);
        __sincosf(0.5f * (w0 + w2), &sa0, &ca0);
        __sincosf(0.5f * (w0 - w2), &sa1, &ca1);
        // U_rot = RZ(w2) RY(w1) RZ(w0)
        const f2 R00 = mk2( cw * ca0, -cw * sa0);
        const f2 R01 = mk2(-sw * ca1, -sw * sa1);
        const f2 R10 = mk2( sw * ca1, -sw * sa1);
        const f2 R11 = mk2( cw * ca0,  cw * sa0);
        auto cm = [](f2 a, f2 bb) { return mk2(a[0]*bb[0] - a[1]*bb[1], a[0]*bb[1] + a[1]*bb[0]); };
        const f2 U00 = cm(R00, E00) + cm(R01, E10);
        const f2 U01 = cm(R00, E01) + cm(R01, E11);
        const f2 U10 = cm(R10, E00) + cm(R11, E10);
        const f2 U11 = cm(R10, E01) + cm(R11, E11);
        gmat[wv][g][0] = make_float4(U00[0], U00[1], U01[0], U01[1]);
        gmat[wv][g][1] = make_float4(U11[0], U11[1], U10[0], U10[1]);
    }
    __syncthreads();

    // ---- state: 16 amps/lane, planar re/im packed 2-per-f2 ----
    // amp storage index = (lane<<4) | (r<<1) | slot
    f2 sre[8], sim[8];
    #pragma unroll
    for (int r = 0; r < 8; ++r) { sre[r] = mk2(0.03125f, 0.03125f); sim[r] = mk2(0.f, 0.f); }

    const float4 (*gm)[2] = gmat[wv];

    #define GATE(L,K) apply_gate<L,K>(sre, sim, gm, lane);
    #define LAYER(L) GATE(L,0) GATE(L,1) GATE(L,2) GATE(L,3) GATE(L,4) \
                     GATE(L,5) GATE(L,6) GATE(L,7) GATE(L,8) GATE(L,9)
    LAYER(0)
    LAYER(1)
    LAYER(2)
    LAYER(3)
    #undef LAYER
    #undef GATE

    // ---- measurement: probs then 4-bit FWHT over register index ----
    float w[16];
    #pragma unroll
    for (int r = 0; r < 8; ++r) {
        const f2 p2 = ffma(sre[r], sre[r], sim[r] * sim[r]);
        w[2 * r] = p2[0]; w[2 * r + 1] = p2[1];
    }
    #pragma unroll
    for (int bit = 1; bit < 16; bit <<= 1) {
        #pragma unroll
        for (int j = 0; j < 16; ++j) {
            if (!(j & bit)) {
                const float a = w[j], c = w[j | bit];
                w[j] = a + c; w[j | bit] = a - c;
            }
        }
    }
    // w[t] = sum_j (-1)^{popc(j&t)} p[j]

    float feats[NM];
    #pragma unroll
    for (int f = 0; f < NM; ++f) {
        const unsigned M = (f < NQ) ? TB.row[NLAY][f]
                                    : (TB.row[NLAY][f - NQ] ^ TB.row[NLAY][(f - NQ + 1) % NQ]);
        const int Ml = (int)(M >> 4), Mj = (int)(M & 15u);
        const float s = w[Mj];
        const int lsgn = __popc((unsigned)lane & (unsigned)Ml) & 1;
        feats[f] = lsgn ? -s : s;
    }
    red_stage<1>(feats);
    red_stage<2>(feats);
    red_stage<4>(feats);
    red_stage<8>(feats);
    red_stage<16>(feats);
    red_stage<32>(feats);

    // ---- MLP head: lanes 0..31 each one hidden unit ----
    float part = 0.f;
    if (lane < HID) {
        float acc = b1[lane];
        #pragma unroll
        for (int mm = 0; mm < NM; ++mm) acc = fmaf(feats[mm], W1[lane * NM + mm], acc);
        const float sg = 1.f / (1.f + __expf(-acc));
        part = acc * sg * W2[lane];
    }
    part += xlane<32>(part);
    part += xlane<16>(part);
    part += xlane<8>(part);
    part += xlane<4>(part);
    part += xlane<2>(part);
    part += xlane<1>(part);
    if (lane == 0) out[b] = part + b2[0];
}

extern "C" void kernel_launch(void* const* d_in, const int* in_sizes, int n_in,
                              void* d_out, int out_size, void* d_ws, size_t ws_size,
                              hipStream_t stream) {
    (void)in_sizes; (void)n_in; (void)out_size; (void)d_ws; (void)ws_size;
    const float* theta = (const float*)d_in[0];
    const float* rotw  = (const float*)d_in[1];
    const float* esc   = (const float*)d_in[2];
    const float* ebi   = (const float*)d_in[3];
    const float* W1    = (const float*)d_in[4];
    const float* b1    = (const float*)d_in[5];
    const float* W2    = (const float*)d_in[6];
    const float* b2    = (const float*)d_in[7];
    float* out = (float*)d_out;

    qrh_kernel<<<BATCH / 4, 256, 0, stream>>>(theta, rotw, esc, ebi, W1, b1, W2, b2, out);
}